// Round 4
// baseline (241.088 us; speedup 1.0000x reference)
//
#include <hip/hip_runtime.h>
#include <hip/hip_cooperative_groups.h>
#include <math.h>

namespace cg = cooperative_groups;

#define Bn 256
#define Cn 3
#define Hn 224
#define Wn 224
#define Sn 20
#define Mn 10
#define NFEAT 5
#define NHID 100
#define NOUT 10
#define NPROD 20            // producer blocks (one per s)
#define CONSUMER NPROD      // block 20 = head consumer

// Single cooperative kernel. Blocks 0..19: one thread per flat sample
// t = s*256 + b (s = blockIdx, b = threadIdx); write samples/logprob to ws.
// Block 20: preloads all head weights into LDS (and pre-reduces the collapsed
// final-FC wsum) WHILE producers run, grid.sync(), then computes both outputs.
// Identities exploited (see prior rounds): reshape makes output row b' consume
// 20 contiguous flat samples; adj=ones collapses both graph convs to S-sums;
// final FC collapses to a 10x10 wsum.
__global__ __launch_bounds__(256, 1) void k_all(
    const float* __restrict__ x, const float* __restrict__ u_cat,
    const float* __restrict__ z, const float* __restrict__ mg,
    const float* __restrict__ w1, const float* __restrict__ b1,
    const float* __restrict__ w2, const float* __restrict__ b2,
    const float* __restrict__ wf, const float* __restrict__ bf,
    float* __restrict__ samples, float* __restrict__ logprob,
    float* __restrict__ out)
{
    cg::grid_group grid = cg::this_grid();
    const int blk = blockIdx.x;
    const int tid = threadIdx.x;

    // producer LDS
    __shared__ float p[6 * Mn];
    __shared__ float bk[Mn][8];
    // consumer LDS
    __shared__ __align__(16) float b1L[NHID];
    __shared__ __align__(16) float w1L[NHID * 8];    // [j][f], stride 8 (16B-aligned rows)
    __shared__ __align__(16) float w2L[NHID * 16];   // [j][k], stride 16
    __shared__ float b2L[NOUT];
    __shared__ float bfL[NOUT];
    __shared__ float wsumL[NOUT * NOUT];             // [k*10+o]
    __shared__ float sh_gv[NOUT][Bn];
    __shared__ float sh_part[NOUT][16];
    __shared__ float sh_max[NOUT];
    __shared__ float sh_lse[NOUT];

    if (blk < NPROD) {
        // ---------------- producer: sample s = blk, batch b = tid ----------------
        const int s = blk;
        const int b = tid;
        if (b < 6 * Mn) p[b] = mg[b];
        __syncthreads();
        if (b < Mn) {
            const float mux = p[b * 6 + 1];
            const float muy = p[b * 6 + 2];
            const float sx  = expf(p[b * 6 + 3]);
            const float sy  = expf(p[b * 6 + 4]);
            const float r   = tanhf(p[b * 6 + 5]);
            const float sq  = sqrtf(1.f - r * r);
            bk[b][0] = mux; bk[b][1] = muy; bk[b][2] = sx; bk[b][3] = sy;
            bk[b][4] = r;   bk[b][5] = sq;
            bk[b][6] = logf(6.283185307179586f * sx * sy * sq);
        }
        __syncthreads();

        // per-b mixture CDF (value = p0[(b*10+m)>>8])
        float raw[Mn];
#pragma unroll
        for (int m = 0; m < Mn; ++m) raw[m] = p[((b * Mn + m) >> 8) * 6 + 0];
        float mx = raw[0];
#pragma unroll
        for (int m = 1; m < Mn; ++m) mx = fmaxf(mx, raw[m]);
        float e[Mn];
        float sum = 0.f;
#pragma unroll
        for (int m = 0; m < Mn; ++m) { e[m] = expf(raw[m] - mx); sum += e[m]; }

        const int t = s * Bn + b;
        const float u = u_cat[t];
        float c = 0.f;
        int idx = 0;
        bool found = false;
#pragma unroll
        for (int m = 0; m < Mn; ++m) {
            c += e[m] / sum;
            if (!found && u < c) { idx = m; found = true; }
        }
        const int g = (b * Mn + idx) >> 8;

        const float mux = bk[g][0], muy = bk[g][1];
        const float sx = bk[g][2], sy = bk[g][3];
        const float r = bk[g][4], sq = bk[g][5], lterm = bk[g][6];

        const float z1 = z[t * 2 + 0];
        const float z2 = z[t * 2 + 1];

        const float px = mux + sx * z1;
        const float py = muy + sy * (r * z1 + sq * z2);
        const float zx = (px - mux) / sx;
        const float zy = (py - muy) / sy;
        const float omr2 = 1.f - r * r;
        logprob[t] = -(zx * zx - 2.f * r * zx * zy + zy * zy) / (2.f * omr2) - lterm;

        const float lx = tanhf(px);
        const float ly = tanhf(py);
        const float vr = 0.5f * (lx + 1.f) * (float)Hn - 0.1f;   // ref uses H for both
        const float vc = 0.5f * (ly + 1.f) * (float)Hn - 0.1f;
        int row = (int)vr; row = min(max(row, 0), Hn - 1);
        int col = (int)vc; col = min(max(col, 0), Wn - 1);

        const int base = b * Cn * Hn * Wn + row * Wn + col;
        const int o5 = t * NFEAT;
        samples[o5 + 0] = x[base + 0 * Hn * Wn];
        samples[o5 + 1] = x[base + 1 * Hn * Wn];
        samples[o5 + 2] = x[base + 2 * Hn * Wn];
        samples[o5 + 3] = lx;
        samples[o5 + 4] = ly;
    } else {
        // ---------------- consumer: preload head weights while producers run ----
        for (int i = tid; i < NHID; i += 256) b1L[i] = b1[i];
        for (int i = tid; i < NHID * NFEAT; i += 256) {
            const int f = i / NHID, j = i % NHID;
            w1L[j * 8 + f] = w1[i];                  // transpose to [j][f]
        }
        for (int i = tid; i < NHID * NOUT; i += 256) {
            const int j = i / NOUT, k = i % NOUT;
            w2L[j * 16 + k] = w2[i];
        }
        if (tid < NOUT) { b2L[tid] = b2[tid]; bfL[tid] = bf[tid]; }
        if (tid < NOUT * NOUT) {
            const int k = tid / NOUT, o = tid % NOUT;
            float w = 0.f;
            for (int s = 0; s < Sn; ++s) w += wf[(s * NOUT + k) * NOUT + o];
            wsumL[tid] = w;
        }
    }

    grid.sync();

    if (blk != CONSUMER) return;

    // ---------------- head: one thread per output row b ----------------
    const int b = tid;

    // output 1: full_log_prob[b] = sum_s logprob[s*256+b]
    float flp = 0.f;
#pragma unroll
    for (int s = 0; s < Sn; ++s) flp += logprob[s * Bn + b];
    out[Bn * NOUT + b] = flp;

    // fs = sum of this row's 20 contiguous samples (100 floats = 25 float4)
    float fs[NFEAT] = {0.f, 0.f, 0.f, 0.f, 0.f};
    const float4* sp4 = (const float4*)(samples + b * Sn * NFEAT);
#pragma unroll
    for (int v = 0; v < 25; ++v) {
        const float4 q = sp4[v];
        fs[(v * 4 + 0) % NFEAT] += q.x;
        fs[(v * 4 + 1) % NFEAT] += q.y;
        fs[(v * 4 + 2) % NFEAT] += q.z;
        fs[(v * 4 + 3) % NFEAT] += q.w;
    }

    // gv[k] = S * (relu(fs.W1+b1) . W2)[k] + b2[k]   (all weights in LDS)
    float gv[NOUT];
#pragma unroll
    for (int k = 0; k < NOUT; ++k) gv[k] = 0.f;
    for (int j = 0; j < NHID; ++j) {
        const float4 wa = *(const float4*)&w1L[j * 8];
        const float  w4 = w1L[j * 8 + 4];
        float a = b1L[j] + fs[0] * wa.x + fs[1] * wa.y + fs[2] * wa.z
                         + fs[3] * wa.w + fs[4] * w4;
        const float h = fmaxf(a, 0.f);
        const float4 r0 = *(const float4*)&w2L[j * 16];
        const float4 r1 = *(const float4*)&w2L[j * 16 + 4];
        const float2 r2 = *(const float2*)&w2L[j * 16 + 8];
        gv[0] += h * r0.x; gv[1] += h * r0.y; gv[2] += h * r0.z; gv[3] += h * r0.w;
        gv[4] += h * r1.x; gv[5] += h * r1.y; gv[6] += h * r1.z; gv[7] += h * r1.w;
        gv[8] += h * r2.x; gv[9] += h * r2.y;
    }
#pragma unroll
    for (int k = 0; k < NOUT; ++k) {
        gv[k] = (float)Sn * gv[k] + b2L[k];
        sh_gv[k][b] = gv[k];
    }
    __syncthreads();

    // lse[k] = logsumexp over the batch axis (log_softmax axis=0)
    if (b < NOUT * 16) {
        const int k = b >> 4, part = b & 15;
        float m0 = sh_gv[k][part * 16];
        for (int i = 1; i < 16; ++i) m0 = fmaxf(m0, sh_gv[k][part * 16 + i]);
        sh_part[k][part] = m0;
    }
    __syncthreads();
    if (b < NOUT) {
        float m0 = sh_part[b][0];
        for (int i = 1; i < 16; ++i) m0 = fmaxf(m0, sh_part[b][i]);
        sh_max[b] = m0;
    }
    __syncthreads();
    if (b < NOUT * 16) {
        const int k = b >> 4, part = b & 15;
        const float m0 = sh_max[k];
        float sacc = 0.f;
        for (int i = 0; i < 16; ++i) sacc += expf(sh_gv[k][part * 16 + i] - m0);
        sh_part[k][part] = sacc;
    }
    __syncthreads();
    if (b < NOUT) {
        float sacc = 0.f;
        for (int i = 0; i < 16; ++i) sacc += sh_part[b][i];
        sh_lse[b] = sh_max[b] + logf(sacc);
    }
    __syncthreads();

    // logits + softmax
    float lg[NOUT];
#pragma unroll
    for (int k = 0; k < NOUT; ++k) lg[k] = gv[k] - sh_lse[k];
    float logits[NOUT];
#pragma unroll
    for (int o = 0; o < NOUT; ++o) {
        float a = bfL[o];
#pragma unroll
        for (int k = 0; k < NOUT; ++k) a += lg[k] * wsumL[k * NOUT + o];
        logits[o] = a;
    }
    float mxl = logits[0];
#pragma unroll
    for (int o = 1; o < NOUT; ++o) mxl = fmaxf(mxl, logits[o]);
    float ssum = 0.f;
#pragma unroll
    for (int o = 0; o < NOUT; ++o) { logits[o] = expf(logits[o] - mxl); ssum += logits[o]; }
#pragma unroll
    for (int o = 0; o < NOUT; ++o) out[b * NOUT + o] = logits[o] / ssum;
}

extern "C" void kernel_launch(void* const* d_in, const int* in_sizes, int n_in,
                              void* d_out, int out_size, void* d_ws, size_t ws_size,
                              hipStream_t stream) {
    const float* x   = (const float*)d_in[0];
    const float* u   = (const float*)d_in[1];
    const float* z   = (const float*)d_in[2];
    const float* mg  = (const float*)d_in[3];
    const float* w1  = (const float*)d_in[4];
    const float* b1  = (const float*)d_in[5];
    const float* w2  = (const float*)d_in[6];
    const float* b2  = (const float*)d_in[7];
    const float* wf  = (const float*)d_in[8];
    const float* bf  = (const float*)d_in[9];
    float* out = (float*)d_out;

    float* samples = (float*)d_ws;                     // 5120*5 floats
    float* logprob = samples + Sn * Bn * NFEAT;        // 5120 floats

    void* args[] = { (void*)&x, (void*)&u, (void*)&z, (void*)&mg,
                     (void*)&w1, (void*)&b1, (void*)&w2, (void*)&b2,
                     (void*)&wf, (void*)&bf,
                     (void*)&samples, (void*)&logprob, (void*)&out };
    hipLaunchCooperativeKernel((void*)k_all, dim3(NPROD + 1), dim3(Bn),
                               args, 0, stream);
}

// Round 5
// 212.260 us; speedup vs baseline: 1.1358x; 1.1358x over previous
//
#include <hip/hip_runtime.h>
#include <math.h>

#define Bn 256
#define Cn 3
#define Hn 224
#define Wn 224
#define Sn 20
#define Mn 10
#define NFEAT 5
#define NHID 100
#define NOUT 10
#define NPROD 20            // producer blocks (one per s)
#define CONSUMER NPROD      // block 20 = head consumer

// Single PLAIN kernel (no cooperative launch). Blocks 0..19: one thread per
// flat sample t = s*256 + b; write samples/logprob to ws, then release-store a
// per-block done-flag (agent scope) and exit. Block 20: preloads all head
// weights into LDS while producers run, acquire-spins on the 20 flags, then
// computes both outputs. Flags are poison-safe: consumer waits for the exact
// value 1, which the harness's 0xAA pattern can never equal; no init needed.
// Identities exploited (prior rounds): reshape makes output row b' consume 20
// contiguous flat samples; adj=ones collapses both graph convs to S-sums;
// final FC collapses to a 10x10 wsum.
__global__ __launch_bounds__(256, 1) void k_all(
    const float* __restrict__ x, const float* __restrict__ u_cat,
    const float* __restrict__ z, const float* __restrict__ mg,
    const float* __restrict__ w1, const float* __restrict__ b1,
    const float* __restrict__ w2, const float* __restrict__ b2,
    const float* __restrict__ wf, const float* __restrict__ bf,
    float* __restrict__ samples, float* __restrict__ logprob,
    unsigned int* __restrict__ flags,
    float* __restrict__ out)
{
    const int blk = blockIdx.x;
    const int tid = threadIdx.x;

    // producer LDS
    __shared__ float p[6 * Mn];
    __shared__ float bk[Mn][8];
    // consumer LDS
    __shared__ __align__(16) float b1L[NHID];
    __shared__ __align__(16) float w1L[NHID * 8];    // [j][f], stride 8
    __shared__ __align__(16) float w2L[NHID * 16];   // [j][k], stride 16
    __shared__ float b2L[NOUT];
    __shared__ float bfL[NOUT];
    __shared__ float wsumL[NOUT * NOUT];             // [k*10+o]
    __shared__ float sh_gv[NOUT][Bn];
    __shared__ float sh_part[NOUT][16];
    __shared__ float sh_max[NOUT];
    __shared__ float sh_lse[NOUT];

    if (blk < NPROD) {
        // ---------------- producer: sample s = blk, batch b = tid ------------
        const int s = blk;
        const int b = tid;
        if (b < 6 * Mn) p[b] = mg[b];
        __syncthreads();
        if (b < Mn) {
            const float mux = p[b * 6 + 1];
            const float muy = p[b * 6 + 2];
            const float sx  = expf(p[b * 6 + 3]);
            const float sy  = expf(p[b * 6 + 4]);
            const float r   = tanhf(p[b * 6 + 5]);
            const float sq  = sqrtf(1.f - r * r);
            bk[b][0] = mux; bk[b][1] = muy; bk[b][2] = sx; bk[b][3] = sy;
            bk[b][4] = r;   bk[b][5] = sq;
            bk[b][6] = logf(6.283185307179586f * sx * sy * sq);
        }
        __syncthreads();

        // per-b mixture CDF (value = p0[(b*10+m)>>8])
        float raw[Mn];
#pragma unroll
        for (int m = 0; m < Mn; ++m) raw[m] = p[((b * Mn + m) >> 8) * 6 + 0];
        float mx = raw[0];
#pragma unroll
        for (int m = 1; m < Mn; ++m) mx = fmaxf(mx, raw[m]);
        float e[Mn];
        float sum = 0.f;
#pragma unroll
        for (int m = 0; m < Mn; ++m) { e[m] = expf(raw[m] - mx); sum += e[m]; }

        const int t = s * Bn + b;
        const float u = u_cat[t];
        float c = 0.f;
        int idx = 0;
        bool found = false;
#pragma unroll
        for (int m = 0; m < Mn; ++m) {
            c += e[m] / sum;
            if (!found && u < c) { idx = m; found = true; }
        }
        const int g = (b * Mn + idx) >> 8;

        const float mux = bk[g][0], muy = bk[g][1];
        const float sx = bk[g][2], sy = bk[g][3];
        const float r = bk[g][4], sq = bk[g][5], lterm = bk[g][6];

        const float z1 = z[t * 2 + 0];
        const float z2 = z[t * 2 + 1];

        const float px = mux + sx * z1;
        const float py = muy + sy * (r * z1 + sq * z2);
        const float zx = (px - mux) / sx;
        const float zy = (py - muy) / sy;
        const float omr2 = 1.f - r * r;
        logprob[t] = -(zx * zx - 2.f * r * zx * zy + zy * zy) / (2.f * omr2) - lterm;

        const float lx = tanhf(px);
        const float ly = tanhf(py);
        const float vr = 0.5f * (lx + 1.f) * (float)Hn - 0.1f;   // ref uses H for both
        const float vc = 0.5f * (ly + 1.f) * (float)Hn - 0.1f;
        int row = (int)vr; row = min(max(row, 0), Hn - 1);
        int col = (int)vc; col = min(max(col, 0), Wn - 1);

        const int base = b * Cn * Hn * Wn + row * Wn + col;
        const int o5 = t * NFEAT;
        samples[o5 + 0] = x[base + 0 * Hn * Wn];
        samples[o5 + 1] = x[base + 1 * Hn * Wn];
        samples[o5 + 2] = x[base + 2 * Hn * Wn];
        samples[o5 + 3] = lx;
        samples[o5 + 4] = ly;

        // publish: all stores of this block, then release flag, then exit
        __syncthreads();
        if (tid == 0) {
            __threadfence();   // agent-scope: make global stores visible device-wide
            __hip_atomic_store(&flags[blk], 1u, __ATOMIC_RELEASE,
                               __HIP_MEMORY_SCOPE_AGENT);
        }
        return;
    }

    // ---------------- consumer: preload head weights while producers run ----
    for (int i = tid; i < NHID; i += 256) b1L[i] = b1[i];
    for (int i = tid; i < NHID * NFEAT; i += 256) {
        const int f = i / NHID, j = i % NHID;
        w1L[j * 8 + f] = w1[i];                      // transpose to [j][f]
    }
    for (int i = tid; i < NHID * NOUT; i += 256) {
        const int j = i / NOUT, k = i % NOUT;
        w2L[j * 16 + k] = w2[i];
    }
    if (tid < NOUT) { b2L[tid] = b2[tid]; bfL[tid] = bf[tid]; }
    if (tid < NOUT * NOUT) {
        const int k = tid / NOUT, o = tid % NOUT;
        float w = 0.f;
        for (int s = 0; s < Sn; ++s) w += wf[(s * NOUT + k) * NOUT + o];
        wsumL[tid] = w;
    }

    // wait for all 20 producers (threads 0..19 each spin on one flag)
    if (tid < NPROD) {
        while (__hip_atomic_load(&flags[tid], __ATOMIC_ACQUIRE,
                                 __HIP_MEMORY_SCOPE_AGENT) != 1u) {
            __builtin_amdgcn_s_sleep(1);
        }
    }
    __syncthreads();
    __threadfence();   // acquire side: invalidate caches before reading ws

    // ---------------- head: one thread per output row b ----------------
    const int b = tid;

    // output 1: full_log_prob[b] = sum_s logprob[s*256+b]
    float flp = 0.f;
#pragma unroll
    for (int s = 0; s < Sn; ++s) flp += logprob[s * Bn + b];
    out[Bn * NOUT + b] = flp;

    // fs = sum of this row's 20 contiguous samples (100 floats = 25 float4)
    float fs[NFEAT] = {0.f, 0.f, 0.f, 0.f, 0.f};
    const float4* sp4 = (const float4*)(samples + b * Sn * NFEAT);
#pragma unroll
    for (int v = 0; v < 25; ++v) {
        const float4 q = sp4[v];
        fs[(v * 4 + 0) % NFEAT] += q.x;
        fs[(v * 4 + 1) % NFEAT] += q.y;
        fs[(v * 4 + 2) % NFEAT] += q.z;
        fs[(v * 4 + 3) % NFEAT] += q.w;
    }

    // gv[k] = S * (relu(fs.W1+b1) . W2)[k] + b2[k]   (all weights in LDS)
    float gv[NOUT];
#pragma unroll
    for (int k = 0; k < NOUT; ++k) gv[k] = 0.f;
    for (int j = 0; j < NHID; ++j) {
        const float4 wa = *(const float4*)&w1L[j * 8];
        const float  w4 = w1L[j * 8 + 4];
        float a = b1L[j] + fs[0] * wa.x + fs[1] * wa.y + fs[2] * wa.z
                         + fs[3] * wa.w + fs[4] * w4;
        const float h = fmaxf(a, 0.f);
        const float4 r0 = *(const float4*)&w2L[j * 16];
        const float4 r1 = *(const float4*)&w2L[j * 16 + 4];
        const float2 r2 = *(const float2*)&w2L[j * 16 + 8];
        gv[0] += h * r0.x; gv[1] += h * r0.y; gv[2] += h * r0.z; gv[3] += h * r0.w;
        gv[4] += h * r1.x; gv[5] += h * r1.y; gv[6] += h * r1.z; gv[7] += h * r1.w;
        gv[8] += h * r2.x; gv[9] += h * r2.y;
    }
#pragma unroll
    for (int k = 0; k < NOUT; ++k) {
        gv[k] = (float)Sn * gv[k] + b2L[k];
        sh_gv[k][b] = gv[k];
    }
    __syncthreads();

    // lse[k] = logsumexp over the batch axis (log_softmax axis=0)
    if (b < NOUT * 16) {
        const int k = b >> 4, part = b & 15;
        float m0 = sh_gv[k][part * 16];
        for (int i = 1; i < 16; ++i) m0 = fmaxf(m0, sh_gv[k][part * 16 + i]);
        sh_part[k][part] = m0;
    }
    __syncthreads();
    if (b < NOUT) {
        float m0 = sh_part[b][0];
        for (int i = 1; i < 16; ++i) m0 = fmaxf(m0, sh_part[b][i]);
        sh_max[b] = m0;
    }
    __syncthreads();
    if (b < NOUT * 16) {
        const int k = b >> 4, part = b & 15;
        const float m0 = sh_max[k];
        float sacc = 0.f;
        for (int i = 0; i < 16; ++i) sacc += expf(sh_gv[k][part * 16 + i] - m0);
        sh_part[k][part] = sacc;
    }
    __syncthreads();
    if (b < NOUT) {
        float sacc = 0.f;
        for (int i = 0; i < 16; ++i) sacc += sh_part[b][i];
        sh_lse[b] = sh_max[b] + logf(sacc);
    }
    __syncthreads();

    // logits + softmax
    float lg[NOUT];
#pragma unroll
    for (int k = 0; k < NOUT; ++k) lg[k] = gv[k] - sh_lse[k];
    float logits[NOUT];
#pragma unroll
    for (int o = 0; o < NOUT; ++o) {
        float a = bfL[o];
#pragma unroll
        for (int k = 0; k < NOUT; ++k) a += lg[k] * wsumL[k * NOUT + o];
        logits[o] = a;
    }
    float mxl = logits[0];
#pragma unroll
    for (int o = 1; o < NOUT; ++o) mxl = fmaxf(mxl, logits[o]);
    float ssum = 0.f;
#pragma unroll
    for (int o = 0; o < NOUT; ++o) { logits[o] = expf(logits[o] - mxl); ssum += logits[o]; }
#pragma unroll
    for (int o = 0; o < NOUT; ++o) out[b * NOUT + o] = logits[o] / ssum;
}

extern "C" void kernel_launch(void* const* d_in, const int* in_sizes, int n_in,
                              void* d_out, int out_size, void* d_ws, size_t ws_size,
                              hipStream_t stream) {
    const float* x   = (const float*)d_in[0];
    const float* u   = (const float*)d_in[1];
    const float* z   = (const float*)d_in[2];
    const float* mg  = (const float*)d_in[3];
    const float* w1  = (const float*)d_in[4];
    const float* b1  = (const float*)d_in[5];
    const float* w2  = (const float*)d_in[6];
    const float* b2  = (const float*)d_in[7];
    const float* wf  = (const float*)d_in[8];
    const float* bf  = (const float*)d_in[9];
    float* out = (float*)d_out;

    float* samples = (float*)d_ws;                       // 5120*5 floats
    float* logprob = samples + Sn * Bn * NFEAT;          // 5120 floats
    unsigned int* flags = (unsigned int*)(logprob + Sn * Bn);  // 20 uints

    hipLaunchKernelGGL(k_all, dim3(NPROD + 1), dim3(Bn), 0, stream,
                       x, u, z, mg, w1, b1, w2, b2, wf, bf,
                       samples, logprob, flags, out);
}

// Round 6
// 210.828 us; speedup vs baseline: 1.1435x; 1.0068x over previous
//
#include <hip/hip_runtime.h>
#include <math.h>

#define Bn 256
#define Cn 3
#define Hn 224
#define Wn 224
#define Sn 20
#define Mn 10
#define NFEAT 5
#define NHID 100
#define NOUT 10
#define NPROD 20            // producer blocks (one per s)

// Single PLAIN kernel. Block 0 = consumer (dispatched first so its weight
// preload overlaps the producers). Blocks 1..20 = producers: one thread per
// flat sample t = (blk-1)*256 + tid; write samples/logprob to ws, then
// release-store a per-block done-flag (agent scope — this alone orders and
// publishes the prior global stores; no extra __threadfence needed) and exit.
// Consumer preloads all head weights into LDS while producers run,
// acquire-spins on the 20 flags (threads 0..19, then __syncthreads — the
// standard one-thread-acquires/barrier/all-read pattern), then computes both
// outputs. Flags are poison-safe: we wait for the literal 1, which the 0xAA
// pattern can never equal; flags only transition 0xAAAAAAAA -> 1 per launch.
// Identities exploited (prior rounds): reshape makes output row b' consume 20
// contiguous flat samples; adj=ones collapses both graph convs to S-sums;
// final FC collapses to a 10x10 wsum.
__global__ __launch_bounds__(256, 1) void k_all(
    const float* __restrict__ x, const float* __restrict__ u_cat,
    const float* __restrict__ z, const float* __restrict__ mg,
    const float* __restrict__ w1, const float* __restrict__ b1,
    const float* __restrict__ w2, const float* __restrict__ b2,
    const float* __restrict__ wf, const float* __restrict__ bf,
    float* __restrict__ samples, float* __restrict__ logprob,
    unsigned int* __restrict__ flags,
    float* __restrict__ out)
{
    const int blk = blockIdx.x;
    const int tid = threadIdx.x;

    // producer LDS
    __shared__ float p[6 * Mn];
    __shared__ float bk[Mn][8];
    // consumer LDS
    __shared__ __align__(16) float b1L[NHID];
    __shared__ __align__(16) float w1L[NHID * 8];    // [j][f], stride 8
    __shared__ __align__(16) float w2L[NHID * 16];   // [j][k], stride 16
    __shared__ float b2L[NOUT];
    __shared__ float bfL[NOUT];
    __shared__ float wsumL[NOUT * NOUT];             // [k*10+o]
    __shared__ float sh_gv[NOUT][Bn];
    __shared__ float sh_part[NOUT][16];
    __shared__ float sh_max[NOUT];
    __shared__ float sh_lse[NOUT];

    if (blk != 0) {
        // ---------------- producer: sample s = blk-1, batch b = tid ----------
        const int s = blk - 1;
        const int b = tid;
        if (b < 6 * Mn) p[b] = mg[b];
        __syncthreads();
        if (b < Mn) {
            const float mux = p[b * 6 + 1];
            const float muy = p[b * 6 + 2];
            const float sx  = expf(p[b * 6 + 3]);
            const float sy  = expf(p[b * 6 + 4]);
            const float r   = tanhf(p[b * 6 + 5]);
            const float sq  = sqrtf(1.f - r * r);
            bk[b][0] = mux; bk[b][1] = muy; bk[b][2] = sx; bk[b][3] = sy;
            bk[b][4] = r;   bk[b][5] = sq;
            bk[b][6] = logf(6.283185307179586f * sx * sy * sq);
        }
        __syncthreads();

        // per-b mixture CDF (value = p0[(b*10+m)>>8])
        float raw[Mn];
#pragma unroll
        for (int m = 0; m < Mn; ++m) raw[m] = p[((b * Mn + m) >> 8) * 6 + 0];
        float mx = raw[0];
#pragma unroll
        for (int m = 1; m < Mn; ++m) mx = fmaxf(mx, raw[m]);
        float e[Mn];
        float sum = 0.f;
#pragma unroll
        for (int m = 0; m < Mn; ++m) { e[m] = expf(raw[m] - mx); sum += e[m]; }

        const int t = s * Bn + b;
        const float u = u_cat[t];
        float c = 0.f;
        int idx = 0;
        bool found = false;
#pragma unroll
        for (int m = 0; m < Mn; ++m) {
            c += e[m] / sum;
            if (!found && u < c) { idx = m; found = true; }
        }
        const int g = (b * Mn + idx) >> 8;

        const float mux = bk[g][0], muy = bk[g][1];
        const float sx = bk[g][2], sy = bk[g][3];
        const float r = bk[g][4], sq = bk[g][5], lterm = bk[g][6];

        const float z1 = z[t * 2 + 0];
        const float z2 = z[t * 2 + 1];

        const float px = mux + sx * z1;
        const float py = muy + sy * (r * z1 + sq * z2);
        const float zx = (px - mux) / sx;
        const float zy = (py - muy) / sy;
        const float omr2 = 1.f - r * r;
        logprob[t] = -(zx * zx - 2.f * r * zx * zy + zy * zy) / (2.f * omr2) - lterm;

        const float lx = tanhf(px);
        const float ly = tanhf(py);
        const float vr = 0.5f * (lx + 1.f) * (float)Hn - 0.1f;   // ref uses H for both
        const float vc = 0.5f * (ly + 1.f) * (float)Hn - 0.1f;
        int row = (int)vr; row = min(max(row, 0), Hn - 1);
        int col = (int)vc; col = min(max(col, 0), Wn - 1);

        const int base = b * Cn * Hn * Wn + row * Wn + col;
        const int o5 = t * NFEAT;
        samples[o5 + 0] = x[base + 0 * Hn * Wn];
        samples[o5 + 1] = x[base + 1 * Hn * Wn];
        samples[o5 + 2] = x[base + 2 * Hn * Wn];
        samples[o5 + 3] = lx;
        samples[o5 + 4] = ly;

        // publish: block's stores done, then ONE release store (orders+flushes)
        __syncthreads();
        if (tid == 0) {
            __hip_atomic_store(&flags[s], 1u, __ATOMIC_RELEASE,
                               __HIP_MEMORY_SCOPE_AGENT);
        }
        return;
    }

    // ---------------- consumer: preload head weights while producers run ----
    for (int i = tid; i < NHID; i += 256) b1L[i] = b1[i];
    for (int i = tid; i < NHID * NFEAT; i += 256) {
        const int f = i / NHID, j = i % NHID;
        w1L[j * 8 + f] = w1[i];                      // transpose to [j][f]
    }
    for (int i = tid; i < NHID * NOUT; i += 256) {
        const int j = i / NOUT, k = i % NOUT;
        w2L[j * 16 + k] = w2[i];
    }
    if (tid < NOUT) { b2L[tid] = b2[tid]; bfL[tid] = bf[tid]; }
    if (tid < NOUT * NOUT) {
        const int k = tid / NOUT, o = tid % NOUT;
        float w = 0.f;
        for (int s = 0; s < Sn; ++s) w += wf[(s * NOUT + k) * NOUT + o];
        wsumL[tid] = w;
    }

    // wait for all 20 producers (threads 0..19 each acquire-spin on one flag)
    if (tid < NPROD) {
        while (__hip_atomic_load(&flags[tid], __ATOMIC_ACQUIRE,
                                 __HIP_MEMORY_SCOPE_AGENT) != 1u) {
            __builtin_amdgcn_s_sleep(1);
        }
    }
    __syncthreads();   // barrier propagates the acquires block-wide

    // ---------------- head: one thread per output row b ----------------
    const int b = tid;

    // output 1: full_log_prob[b] = sum_s logprob[s*256+b]
    float flp = 0.f;
#pragma unroll
    for (int s = 0; s < Sn; ++s) flp += logprob[s * Bn + b];
    out[Bn * NOUT + b] = flp;

    // fs = sum of this row's 20 contiguous samples (100 floats = 25 float4)
    float fs[NFEAT] = {0.f, 0.f, 0.f, 0.f, 0.f};
    const float4* sp4 = (const float4*)(samples + b * Sn * NFEAT);
#pragma unroll
    for (int v = 0; v < 25; ++v) {
        const float4 q = sp4[v];
        fs[(v * 4 + 0) % NFEAT] += q.x;
        fs[(v * 4 + 1) % NFEAT] += q.y;
        fs[(v * 4 + 2) % NFEAT] += q.z;
        fs[(v * 4 + 3) % NFEAT] += q.w;
    }

    // gv[k] = S * (relu(fs.W1+b1) . W2)[k] + b2[k]   (all weights in LDS)
    float gv[NOUT];
#pragma unroll
    for (int k = 0; k < NOUT; ++k) gv[k] = 0.f;
    for (int j = 0; j < NHID; ++j) {
        const float4 wa = *(const float4*)&w1L[j * 8];
        const float  w4 = w1L[j * 8 + 4];
        float a = b1L[j] + fs[0] * wa.x + fs[1] * wa.y + fs[2] * wa.z
                         + fs[3] * wa.w + fs[4] * w4;
        const float h = fmaxf(a, 0.f);
        const float4 r0 = *(const float4*)&w2L[j * 16];
        const float4 r1 = *(const float4*)&w2L[j * 16 + 4];
        const float2 r2 = *(const float2*)&w2L[j * 16 + 8];
        gv[0] += h * r0.x; gv[1] += h * r0.y; gv[2] += h * r0.z; gv[3] += h * r0.w;
        gv[4] += h * r1.x; gv[5] += h * r1.y; gv[6] += h * r1.z; gv[7] += h * r1.w;
        gv[8] += h * r2.x; gv[9] += h * r2.y;
    }
#pragma unroll
    for (int k = 0; k < NOUT; ++k) {
        gv[k] = (float)Sn * gv[k] + b2L[k];
        sh_gv[k][b] = gv[k];
    }
    __syncthreads();

    // lse[k] = logsumexp over the batch axis (log_softmax axis=0)
    if (b < NOUT * 16) {
        const int k = b >> 4, part = b & 15;
        float m0 = sh_gv[k][part * 16];
        for (int i = 1; i < 16; ++i) m0 = fmaxf(m0, sh_gv[k][part * 16 + i]);
        sh_part[k][part] = m0;
    }
    __syncthreads();
    if (b < NOUT) {
        float m0 = sh_part[b][0];
        for (int i = 1; i < 16; ++i) m0 = fmaxf(m0, sh_part[b][i]);
        sh_max[b] = m0;
    }
    __syncthreads();
    if (b < NOUT * 16) {
        const int k = b >> 4, part = b & 15;
        const float m0 = sh_max[k];
        float sacc = 0.f;
        for (int i = 0; i < 16; ++i) sacc += expf(sh_gv[k][part * 16 + i] - m0);
        sh_part[k][part] = sacc;
    }
    __syncthreads();
    if (b < NOUT) {
        float sacc = 0.f;
        for (int i = 0; i < 16; ++i) sacc += sh_part[b][i];
        sh_lse[b] = sh_max[b] + logf(sacc);
    }
    __syncthreads();

    // logits + softmax
    float lg[NOUT];
#pragma unroll
    for (int k = 0; k < NOUT; ++k) lg[k] = gv[k] - sh_lse[k];
    float logits[NOUT];
#pragma unroll
    for (int o = 0; o < NOUT; ++o) {
        float a = bfL[o];
#pragma unroll
        for (int k = 0; k < NOUT; ++k) a += lg[k] * wsumL[k * NOUT + o];
        logits[o] = a;
    }
    float mxl = logits[0];
#pragma unroll
    for (int o = 1; o < NOUT; ++o) mxl = fmaxf(mxl, logits[o]);
    float ssum = 0.f;
#pragma unroll
    for (int o = 0; o < NOUT; ++o) { logits[o] = expf(logits[o] - mxl); ssum += logits[o]; }
#pragma unroll
    for (int o = 0; o < NOUT; ++o) out[b * NOUT + o] = logits[o] / ssum;
}

extern "C" void kernel_launch(void* const* d_in, const int* in_sizes, int n_in,
                              void* d_out, int out_size, void* d_ws, size_t ws_size,
                              hipStream_t stream) {
    const float* x   = (const float*)d_in[0];
    const float* u   = (const float*)d_in[1];
    const float* z   = (const float*)d_in[2];
    const float* mg  = (const float*)d_in[3];
    const float* w1  = (const float*)d_in[4];
    const float* b1  = (const float*)d_in[5];
    const float* w2  = (const float*)d_in[6];
    const float* b2  = (const float*)d_in[7];
    const float* wf  = (const float*)d_in[8];
    const float* bf  = (const float*)d_in[9];
    float* out = (float*)d_out;

    float* samples = (float*)d_ws;                       // 5120*5 floats
    float* logprob = samples + Sn * Bn * NFEAT;          // 5120 floats
    unsigned int* flags = (unsigned int*)(logprob + Sn * Bn);  // 20 uints

    hipLaunchKernelGGL(k_all, dim3(NPROD + 1), dim3(Bn), 0, stream,
                       x, u, z, mg, w1, b1, w2, b2, wf, bf,
                       samples, logprob, flags, out);
}